// Round 17
// baseline (40.277 us; speedup 1.0000x reference)
//
#include <hip/hip_runtime.h>

#define NF 40
#define KD 64

typedef float f32x4 __attribute__((ext_vector_type(4)));
typedef _Float16 f16x8 __attribute__((ext_vector_type(8)));
typedef _Float16 f16x4 __attribute__((ext_vector_type(4)));

// One sample per WAVE: no cross-wave data sharing, single block barrier (LUT).
// Intra-wave LDS write->read needs no barrier: DS pipe is in-order per wave;
// compiler keeps same-array DS order (wave_barrier fences guard reordering).
__global__ __launch_bounds__(256, 4)
void afm_kernel(const int* __restrict__ x,
                const float* __restrict__ lin_table,
                const float* __restrict__ V_table,
                const float* __restrict__ W1,
                const float* __restrict__ b1,
                const float* __restrict__ W2,
                const float* __restrict__ b2,
                const float* __restrict__ Wf,
                const float* __restrict__ bf,
                float* __restrict__ out)
{
    __shared__ _Float16 ew[4][NF][72];   // per-wave embeddings (stride 72 f16)
    __shared__ _Float16 Qw[4][48][72];   // per-wave exp(score); pads zero
    __shared__ unsigned short lut[832];  // p -> (i<<8|j)

    const int tid = threadIdx.x;
    const int w = tid >> 6;
    const int lane = tid & 63;
    const int l15 = lane & 15;
    const int lhi = lane >> 4;
    const int smp = blockIdx.x * 4 + w;  // sample id

    // ---- block-cooperative pair LUT
    for (int p0 = tid; p0 < 832; p0 += 256) {
        int p = p0 > 819 ? 819 : p0;
        int i = (int)((81.0f - sqrtf(6561.0f - 8.0f * (float)p)) * 0.5f);
        int off = (i * (81 - i)) >> 1;
        if ((((i + 1) * (80 - i)) >> 1) <= p) { ++i; off = (i * (81 - i)) >> 1; }
        else if (off > p)                     { --i; off = (i * (81 - i)) >> 1; }
        lut[p0] = (unsigned short)((i << 8) | (i + (p - off)));
    }

    _Float16* e = &ew[w][0][0];
    _Float16* Q = &Qw[w][0][0];

    // ---- per-wave: zero Q pads (rows 0..39 cols 40..63; rows 40..47 all)
    {
        f16x8 zh = {0, 0, 0, 0, 0, 0, 0, 0};
        for (int t = lane; t < 192; t += 64) {
            if (t < 120) {
                int r = t / 3, c8 = t - r * 3;
                *reinterpret_cast<f16x8*>(Q + r * 72 + 40 + c8 * 8) = zh;
            } else {
                int t2 = t - 120, r9 = t2 / 9;
                *reinterpret_cast<f16x8*>(Q + (40 + r9) * 72 + (t2 - r9 * 9) * 8) = zh;
            }
        }
    }

    // ---- per-wave gather: 640 float4 / 64 lanes = 10 each
    for (int q = lane; q < NF * (KD / 4); q += 64) {
        int i = q >> 4, k4 = q & 15;
        int ix = x[smp * NF + i];
        float4 v = reinterpret_cast<const float4*>(V_table + (size_t)ix * KD)[k4];
        f16x4 hv = {(_Float16)v.x, (_Float16)v.y, (_Float16)v.z, (_Float16)v.w};
        *reinterpret_cast<f16x4*>(e + i * 72 + k4 * 4) = hv;
    }
    float linv = (lane < NF) ? lin_table[x[smp * NF + lane]] : 0.0f;

    // ---- per-lane constants (global loads overlap other waves' progress)
    f16x8 Af[4][2];
    #pragma unroll
    for (int at = 0; at < 4; ++at) {
        #pragma unroll
        for (int ks = 0; ks < 2; ++ks) {
            f16x8 t;
            #pragma unroll
            for (int el = 0; el < 8; ++el)
                t[el] = (_Float16)W1[(ks * 32 + lhi * 8 + el) * KD + at * 16 + l15];
            Af[at][ks] = t;
        }
    }
    f32x4 b1v[4], w2v[4];
    #pragma unroll
    for (int at = 0; at < 4; ++at) {
        b1v[at] = *reinterpret_cast<const f32x4*>(b1 + at * 16 + lhi * 4);
        w2v[at] = *reinterpret_cast<const f32x4*>(W2 + at * 16 + lhi * 4);
    }
    float wfv[4];
    #pragma unroll
    for (int nt = 0; nt < 4; ++nt) wfv[nt] = Wf[nt * 16 + l15];
    const float bf0 = bf[0];

    __syncthreads();   // ONLY barrier: lut visible to all waves
    __builtin_amdgcn_wave_barrier();

    // ---- score GEMM: all 52 tiles (i<=j pairs) in this wave
    const int k0 = lhi * 8;
    for (int mt = 0; mt < 52; ++mt) {
        const int v = lut[mt * 16 + l15];
        const int i = v >> 8;
        const int j = v & 255;
        const _Float16* ei = e + i * 72;
        const _Float16* ej = e + j * 72;
        f16x8 B0 = (*reinterpret_cast<const f16x8*>(ei + k0)) *
                   (*reinterpret_cast<const f16x8*>(ej + k0));
        f16x8 B1 = (*reinterpret_cast<const f16x8*>(ei + k0 + 32)) *
                   (*reinterpret_cast<const f16x8*>(ej + k0 + 32));

        f32x4 d[4];
        #pragma unroll
        for (int at = 0; at < 4; ++at) {
            d[at] = b1v[at];
            d[at] = __builtin_amdgcn_mfma_f32_16x16x32_f16(Af[at][0], B0, d[at], 0, 0, 0);
            d[at] = __builtin_amdgcn_mfma_f32_16x16x32_f16(Af[at][1], B1, d[at], 0, 0, 0);
        }

        float s = 0.0f;
        #pragma unroll
        for (int at = 0; at < 4; ++at) {
            #pragma unroll
            for (int r = 0; r < 4; ++r)
                s = fmaf(fmaxf(d[at][r], 0.0f), w2v[at][r], s);
        }
        s += __shfl_xor(s, 16, 64);
        s += __shfl_xor(s, 32, 64);
        // scores O(+-0.01): exp w/o max-shift safe; softmax shift-invariant.
        float qv = __expf(s);
        if (lhi == 0) {
            _Float16 qh = (_Float16)qv;
            Q[i * 72 + j] = qh;            // mirror write: symmetric scores
            Q[j * 72 + i] = qh;
        }
    }
    __builtin_amdgcn_wave_barrier();

    // ---- PV + we fused, per mt. Z in-register: all-ones-column B fragment
    // gives every lane z for its own D-rows (no LDS roundtrip).
    float acc4[4] = {0.f, 0.f, 0.f, 0.f};
    #pragma unroll
    for (int mt = 0; mt < 3; ++mt) {
        const _Float16* qrow = Q + (mt * 16 + l15) * 72;
        f16x8 aq0 = *reinterpret_cast<const f16x8*>(qrow + lhi * 8);
        f16x8 aq1 = *reinterpret_cast<const f16x8*>(qrow + 32 + lhi * 8);

        f16x8 one0, one1;
        #pragma unroll
        for (int el = 0; el < 8; ++el) {
            one0[el] = (_Float16)1.0f;                        // k = lhi*8+el < 40
            one1[el] = (lhi == 0) ? (_Float16)1.0f : (_Float16)0.0f;
        }
        f32x4 dz = {0.f, 0.f, 0.f, 0.f};
        dz = __builtin_amdgcn_mfma_f32_16x16x32_f16(aq0, one0, dz, 0, 0, 0);
        dz = __builtin_amdgcn_mfma_f32_16x16x32_f16(aq1, one1, dz, 0, 0, 0);
        float rz[4];
        #pragma unroll
        for (int r = 0; r < 4; ++r) {
            int ii = mt * 16 + lhi * 4 + r;
            rz[r] = (ii < NF) ? __builtin_amdgcn_rcpf(dz[r]) : 0.0f;  // no inf*0
        }

        #pragma unroll
        for (int nt = 0; nt < 4; ++nt) {
            const int c = nt * 16 + l15;
            f16x8 bv0, bv1;
            #pragma unroll
            for (int el = 0; el < 8; ++el) {
                bv0[el] = e[(lhi * 8 + el) * 72 + c];                  // rows 0..31
                bv1[el] = (lhi == 0) ? e[(32 + el) * 72 + c]           // rows 32..39
                                     : (_Float16)0.0f;                 // rows 40..63
            }
            f32x4 dq = {0.f, 0.f, 0.f, 0.f};
            dq = __builtin_amdgcn_mfma_f32_16x16x32_f16(aq0, bv0, dq, 0, 0, 0);
            dq = __builtin_amdgcn_mfma_f32_16x16x32_f16(aq1, bv1, dq, 0, 0, 0);

            float a = 0.0f;
            #pragma unroll
            for (int r = 0; r < 4; ++r) {
                int ii = mt * 16 + lhi * 4 + r;
                int iic = ii > 39 ? 39 : ii;       // rz=0 kills clamped rows
                a = fmaf((float)e[iic * 72 + c] * dq[r], rz[r], a);
            }
            acc4[nt] += a;
        }
    }

    // ---- final reductions (all in-wave)
    #pragma unroll
    for (int nt = 0; nt < 4; ++nt) {
        acc4[nt] += __shfl_xor(acc4[nt], 16, 64);
        acc4[nt] += __shfl_xor(acc4[nt], 32, 64);
    }
    float inter = 0.0f;
    #pragma unroll
    for (int nt = 0; nt < 4; ++nt) inter = fmaf(acc4[nt], wfv[nt], inter);
    inter += __shfl_xor(inter, 1, 64);
    inter += __shfl_xor(inter, 2, 64);
    inter += __shfl_xor(inter, 4, 64);
    inter += __shfl_xor(inter, 8, 64);

    linv += __shfl_xor(linv, 32, 64);
    linv += __shfl_xor(linv, 16, 64);
    linv += __shfl_xor(linv, 8, 64);
    linv += __shfl_xor(linv, 4, 64);
    linv += __shfl_xor(linv, 2, 64);
    linv += __shfl_xor(linv, 1, 64);

    if (lane == 0) {
        float z = linv + inter + bf0;
        out[smp] = 1.0f / (1.0f + __expf(-z));
    }
}

extern "C" void kernel_launch(void* const* d_in, const int* in_sizes, int n_in,
                              void* d_out, int out_size, void* d_ws, size_t ws_size,
                              hipStream_t stream) {
    const int*   x         = (const int*)d_in[0];
    const float* lin_table = (const float*)d_in[1];
    const float* V_table   = (const float*)d_in[2];
    const float* W1        = (const float*)d_in[3];
    const float* b1        = (const float*)d_in[4];
    const float* W2        = (const float*)d_in[5];
    const float* b2        = (const float*)d_in[6];
    const float* Wf        = (const float*)d_in[7];
    const float* bf        = (const float*)d_in[8];
    float* out = (float*)d_out;

    const int batch = in_sizes[0] / NF;   // 2048
    afm_kernel<<<batch / 4, 256, 0, stream>>>(x, lin_table, V_table, W1, b1, W2,
                                              b2, Wf, bf, out);
}

// Round 18
// 32.576 us; speedup vs baseline: 1.2364x; 1.2364x over previous
//
#include <hip/hip_runtime.h>

#define NF 40
#define KD 64

typedef float f32x4 __attribute__((ext_vector_type(4)));
typedef _Float16 f16x8 __attribute__((ext_vector_type(8)));
typedef _Float16 f16x4 __attribute__((ext_vector_type(4)));

__global__ __launch_bounds__(256, 4)
void afm_kernel(const int* __restrict__ x,
                const float* __restrict__ lin_table,
                const float* __restrict__ V_table,
                const float* __restrict__ W1,
                const float* __restrict__ b1,
                const float* __restrict__ W2,
                const float* __restrict__ b2,
                const float* __restrict__ Wf,
                const float* __restrict__ bf,
                float* __restrict__ out)
{
    // all tiles stride 72 f16 = 144 B (16B-aligned rows, 4-bank/row rotation)
    __shared__ _Float16 e16[NF][72];     // embeddings [field][k]
    __shared__ _Float16 eT16[KD][72];    // transposed [k][field]; cols 40..71 zero
    __shared__ _Float16 Q16[48][72];     // exp(score); fully zero-init (NaN safety)
    __shared__ unsigned short lut[832];  // p -> (i<<8|j)
    __shared__ float wsum[4];

    const int b = blockIdx.x;
    const int tid = threadIdx.x;
    const int w = tid >> 6;
    const int lane = tid & 63;
    const int l15 = lane & 15;
    const int lhi = lane >> 4;

    // ---- zero-init: ALL of Q16 (MFMA A-side NaN safety), eT16 cols 40..71
    {
        f16x8 zh = {0, 0, 0, 0, 0, 0, 0, 0};
        for (int t = tid; t < 48 * 72 / 8; t += 256)
            reinterpret_cast<f16x8*>(&Q16[0][0])[t] = zh;
        int r = tid >> 2, c8 = tid & 3;            // 256 threads: 64 rows x 4 octs
        *reinterpret_cast<f16x8*>(&eT16[r][40 + 8 * c8]) = zh;
    }
    // ---- pair LUT
    for (int p0 = tid; p0 < 832; p0 += 256) {
        int p = p0 > 819 ? 819 : p0;
        int i = (int)((81.0f - sqrtf(6561.0f - 8.0f * (float)p)) * 0.5f);
        int off = (i * (81 - i)) >> 1;
        if ((((i + 1) * (80 - i)) >> 1) <= p) { ++i; off = (i * (81 - i)) >> 1; }
        else if (off > p)                     { --i; off = (i * (81 - i)) >> 1; }
        lut[p0] = (unsigned short)((i << 8) | (i + (p - off)));
    }

    // ---- gather: coalesced float4 -> f16; write row-major + transposed
    for (int q = tid; q < NF * (KD / 4); q += 256) {
        int i = q >> 4, k4 = q & 15;
        int ix = x[b * NF + i];
        float4 v = reinterpret_cast<const float4*>(V_table + (size_t)ix * KD)[k4];
        f16x4 hv = {(_Float16)v.x, (_Float16)v.y, (_Float16)v.z, (_Float16)v.w};
        *reinterpret_cast<f16x4*>(&e16[i][k4 * 4]) = hv;
        eT16[k4 * 4 + 0][i] = hv[0];
        eT16[k4 * 4 + 1][i] = hv[1];
        eT16[k4 * 4 + 2][i] = hv[2];
        eT16[k4 * 4 + 3][i] = hv[3];
    }
    float linv = (w == 0 && lane < NF) ? lin_table[x[b * NF + lane]] : 0.0f;

    // ---- per-lane constants
    f16x8 Af[4][2];
    #pragma unroll
    for (int at = 0; at < 4; ++at) {
        #pragma unroll
        for (int ks = 0; ks < 2; ++ks) {
            f16x8 t;
            #pragma unroll
            for (int el = 0; el < 8; ++el)
                t[el] = (_Float16)W1[(ks * 32 + lhi * 8 + el) * KD + at * 16 + l15];
            Af[at][ks] = t;
        }
    }
    f32x4 b1v[4], w2v[4];
    #pragma unroll
    for (int at = 0; at < 4; ++at) {
        b1v[at] = *reinterpret_cast<const f32x4*>(b1 + at * 16 + lhi * 4);
        w2v[at] = *reinterpret_cast<const f32x4*>(W2 + at * 16 + lhi * 4);
    }
    const float wfv = Wf[w * 16 + l15];
    const float bf0 = bf[0];
    __syncthreads();

    // ---- score GEMM over i<=j pairs (symmetric), 52 tiles of 16 (R11 form)
    const int k0 = lhi * 8;
    for (int mt = w; mt < 52; mt += 4) {
        const int v = lut[mt * 16 + l15];
        const int i = v >> 8;
        const int j = v & 255;
        const _Float16* ei = &e16[i][0];
        const _Float16* ej = &e16[j][0];
        f16x8 B0 = (*reinterpret_cast<const f16x8*>(ei + k0)) *
                   (*reinterpret_cast<const f16x8*>(ej + k0));
        f16x8 B1 = (*reinterpret_cast<const f16x8*>(ei + k0 + 32)) *
                   (*reinterpret_cast<const f16x8*>(ej + k0 + 32));

        f32x4 d[4];
        #pragma unroll
        for (int at = 0; at < 4; ++at) {
            d[at] = b1v[at];
            d[at] = __builtin_amdgcn_mfma_f32_16x16x32_f16(Af[at][0], B0, d[at], 0, 0, 0);
            d[at] = __builtin_amdgcn_mfma_f32_16x16x32_f16(Af[at][1], B1, d[at], 0, 0, 0);
        }
        float s = 0.0f;
        #pragma unroll
        for (int at = 0; at < 4; ++at) {
            #pragma unroll
            for (int r = 0; r < 4; ++r)
                s = fmaf(fmaxf(d[at][r], 0.0f), w2v[at][r], s);
        }
        s += __shfl_xor(s, 16, 64);
        s += __shfl_xor(s, 32, 64);
        // scores O(+-0.01): exp w/o max-shift safe; softmax shift-invariant.
        float qv = __expf(s);
        if (lhi == 0) {
            _Float16 qh = (_Float16)qv;
            Q16[i][j] = qh;                // mirror write: symmetric scores
            Q16[j][i] = qh;
        }
    }
    __syncthreads();

    // ---- PV, fixed nt = w per wave. B-frags hoisted (2 b128, reused 3x).
    // Z in-register via ones-column MFMA; we fused per mt (b64 eT reads).
    const int c = w * 16 + l15;
    const f16x8 bv0 = *reinterpret_cast<const f16x8*>(&eT16[c][lhi * 8]);
    const f16x8 bv1 = *reinterpret_cast<const f16x8*>(&eT16[c][32 + lhi * 8]);
    f16x8 one0, one1;
    #pragma unroll
    for (int el = 0; el < 8; ++el) {
        one0[el] = (_Float16)1.0f;                                // j < 32
        one1[el] = (lhi == 0) ? (_Float16)1.0f : (_Float16)0.0f;  // j 32..39 only
    }

    float acc = 0.0f;
    #pragma unroll
    for (int mt = 0; mt < 3; ++mt) {
        const _Float16* qrow = &Q16[mt * 16 + l15][0];
        f16x8 aq0 = *reinterpret_cast<const f16x8*>(qrow + lhi * 8);
        f16x8 aq1 = *reinterpret_cast<const f16x8*>(qrow + 32 + lhi * 8);

        f32x4 dz = {0.f, 0.f, 0.f, 0.f};
        dz = __builtin_amdgcn_mfma_f32_16x16x32_f16(aq0, one0, dz, 0, 0, 0);
        dz = __builtin_amdgcn_mfma_f32_16x16x32_f16(aq1, one1, dz, 0, 0, 0);

        f32x4 dq = {0.f, 0.f, 0.f, 0.f};
        dq = __builtin_amdgcn_mfma_f32_16x16x32_f16(aq0, bv0, dq, 0, 0, 0);
        dq = __builtin_amdgcn_mfma_f32_16x16x32_f16(aq1, bv1, dq, 0, 0, 0);

        f16x4 ev4 = *reinterpret_cast<const f16x4*>(&eT16[c][mt * 16 + lhi * 4]);
        #pragma unroll
        for (int r = 0; r < 4; ++r) {
            int ii = mt * 16 + lhi * 4 + r;
            float rz = (ii < NF) ? __builtin_amdgcn_rcpf(dz[r]) : 0.0f;
            acc = fmaf((float)ev4[r] * dq[r], rz, acc);  // dq=0 on pad rows
        }
    }

    // ---- inter = sum_c we[c]*Wf[c]; per-wave partial then cross-wave sum
    acc += __shfl_xor(acc, 16, 64);
    acc += __shfl_xor(acc, 32, 64);          // acc = we[c] on all lanes
    float ip = acc * wfv;
    ip += __shfl_xor(ip, 1, 64);
    ip += __shfl_xor(ip, 2, 64);
    ip += __shfl_xor(ip, 4, 64);
    ip += __shfl_xor(ip, 8, 64);
    if (lane == 0) wsum[w] = ip;
    __syncthreads();

    if (w == 0) {
        linv += __shfl_xor(linv, 32, 64);
        linv += __shfl_xor(linv, 16, 64);
        linv += __shfl_xor(linv, 8, 64);
        linv += __shfl_xor(linv, 4, 64);
        linv += __shfl_xor(linv, 2, 64);
        linv += __shfl_xor(linv, 1, 64);
        if (lane == 0) {
            float z = linv + wsum[0] + wsum[1] + wsum[2] + wsum[3] + bf0;
            out[b] = 1.0f / (1.0f + __expf(-z));
        }
    }
}

extern "C" void kernel_launch(void* const* d_in, const int* in_sizes, int n_in,
                              void* d_out, int out_size, void* d_ws, size_t ws_size,
                              hipStream_t stream) {
    const int*   x         = (const int*)d_in[0];
    const float* lin_table = (const float*)d_in[1];
    const float* V_table   = (const float*)d_in[2];
    const float* W1        = (const float*)d_in[3];
    const float* b1        = (const float*)d_in[4];
    const float* W2        = (const float*)d_in[5];
    const float* b2        = (const float*)d_in[6];
    const float* Wf        = (const float*)d_in[7];
    const float* bf        = (const float*)d_in[8];
    float* out = (float*)d_out;

    const int batch = in_sizes[0] / NF;   // 2048
    afm_kernel<<<batch, 256, 0, stream>>>(x, lin_table, V_table, W1, b1, W2, b2,
                                          Wf, bf, out);
}